// Round 3
// baseline (330.185 us; speedup 1.0000x reference)
//
#include <hip/hip_runtime.h>

#define BATCH 512
#define TLEN  2048
#define NST   24
#define ESTR  28          // floats per ctx row in E table: 24 E + lognorm + 3 pad
#define NCTX  100         // ctx = (c2*5 + c1)*4 + c0  (c2,c1 in 0..4, c0 in 0..3)
#define MAXC  128

__device__ __forceinline__ unsigned short f2bf(float x) {
  unsigned u = __float_as_uint(x);
  u += 0x7FFFu + ((u >> 16) & 1u);
  return (unsigned short)(u >> 16);
}

// R[dst] = sum over edges (src->dst) of A[edge]*f[src]; edges numbered source-major.
__device__ __forceinline__ void at_update(const float* __restrict__ A,
                                          const float* __restrict__ f,
                                          float* __restrict__ R) {
  R[0]  = A[0]*f[0];
  R[1]  = A[1]*f[0];
  R[2]  = A[2]*f[1];
  R[3]  = A[3]*f[2];
  R[4]  = A[4]*f[3]  + A[24]*f[16];
  R[5]  = A[8]*f[4];
  R[6]  = A[9]*f[5];
  R[7]  = A[6]*f[3]  + A[10]*f[6] + A[28]*f[19];
  R[8]  = A[13]*f[7];
  R[9]  = A[14]*f[8];
  R[10] = A[7]*f[3]  + A[12]*f[6] + A[15]*f[9] + A[32]*f[22];
  R[11] = A[17]*f[10];
  R[12] = A[18]*f[11];
  R[13] = A[19]*f[12] + A[20]*f[13];
  R[14] = A[5]*f[3]  + A[25]*f[16];
  R[15] = A[22]*f[14];
  R[16] = A[23]*f[15];
  R[17] = A[11]*f[6] + A[29]*f[19];
  R[18] = A[26]*f[17];
  R[19] = A[27]*f[18];
  R[20] = A[16]*f[9] + A[33]*f[22];
  R[21] = A[30]*f[20];
  R[22] = A[31]*f[21];
  R[23] = A[21]*f[13] + A[34]*f[23];
}

__device__ __forceinline__ float tree_sum24(const float* a) {
  float s0 = a[0]+a[1],   s1 = a[2]+a[3],   s2 = a[4]+a[5],   s3 = a[6]+a[7];
  float s4 = a[8]+a[9],   s5 = a[10]+a[11], s6 = a[12]+a[13], s7 = a[14]+a[15];
  float s8 = a[16]+a[17], s9 = a[18]+a[19], s10= a[20]+a[21], s11= a[22]+a[23];
  float u0 = s0+s1, u1 = s2+s3, u2 = s4+s5, u3 = s6+s7, u4 = s8+s9, u5 = s10+s11;
  return ((u0+u1) + (u2+u3)) + (u4+u5);
}

// ------------------------------------------------------------------
// Builder: A edge values (row softmax) + normalized E table per context.
// ------------------------------------------------------------------
__global__ __launch_bounds__(256) void k_build_tables(
    const float* __restrict__ wt, const float* __restrict__ we,
    float* __restrict__ etab, float* __restrict__ a35out)
{
  __shared__ float lg[NST * 216];
  __shared__ float rmx[NST];
  __shared__ float rrs[NST];
  int tid = threadIdx.x;
  for (int i = tid; i < NST * 216; i += 256) lg[i] = -1e30f;
  __syncthreads();

  for (int e = tid; e < 1073; e += 256) {
    int s, i, j, l, k = -1;
    if (e < 84)        { int ep=e; l=ep&3; int p=ep>>2; if (p<16){i=p>>2;j=p&3;} else {i=4;j=p-16;} s=0; k=ep; }
    else if (e < 104)  { int ep=e-84;  s=1;  i=ep>>2; j=ep&3; l=0; k=84+ep; }
    else if (e < 108)  { int ep=e-104; s=2;  i=ep;    j=0;    l=3; k=104+ep; }
    else if (e < 109)  { s=3; i=0; j=3; l=2; }
    else if (e < 113)  { int ep=e-109; s=4;  i=3; j=2; l=ep;  k=108+ep; }
    else if (e < 129)  { int ep=e-113; s=5;  i=2; j=ep>>2; l=ep&3; k=112+ep; }
    else if (e < 385)  { int ep=e-129; s=6+(ep>>6); int q=ep&63; i=q>>4; j=(q>>2)&3; l=q&3; k=128+ep; }
    else if (e < 401)  { int ep=e-385; s=10; i=ep>>2; j=ep&3; l=3; k=384+ep; }
    else if (e < 405)  { int ep=e-401; s=11; i=ep; j=3; l=0; k=400+ep; }
    else if (e < 409)  { int ep=e-405; s=11; i=ep; j=3; l=2; k=404+ep; }
    else if (e < 412)  { int ep=e-409; s=12; i=3; j=(ep==2)?2:0; l=(ep==1)?2:0; }
    else if (e < 476)  { int ep=e-412; s=13; i=ep>>4; j=(ep>>2)&3; l=ep&3; k=408+ep; }
    else if (e < 1052) { int ep=e-476; s=14+(ep>>6); int q=ep&63; i=q>>4; j=(q>>2)&3; l=q&3; k=472+ep; }
    else if (e < 1068) { int ep=e-1052; s=23; i=ep>>2; j=ep&3; l=5; k=1048+ep; }
    else if (e < 1072) { int ep=e-1068; s=23; i=ep; j=5; l=5; k=1064+ep; }
    else               { s=23; i=5; j=5; l=5; }
    float v = (k < 0) ? 1.0f : we[k];
    lg[s*216 + i*36 + j*6 + l] = v;
  }
  __syncthreads();

  if (tid < NST) {
    float mx = -1e30f;
    for (int x = 0; x < 216; ++x) mx = fmaxf(mx, lg[tid*216 + x]);
    float sum = 0.f;
    for (int x = 0; x < 216; ++x) sum += expf(lg[tid*216 + x] - mx);
    rmx[tid] = mx;
    rrs[tid] = 1.0f / sum;
  }
  __syncthreads();

  if (tid < NCTX) {
    int c2 = tid / 20, c1 = (tid >> 2) % 5, c0 = tid & 3;
    int x = c2*36 + c1*6 + c0;
    float v[NST];
    float m = 1e-30f;
    for (int s = 0; s < NST; ++s) {
      v[s] = expf(lg[s*216 + x] - rmx[s]) * rrs[s];
      m = fmaxf(m, v[s]);
    }
    float im = 1.0f / m;
    for (int s = 0; s < NST; ++s) etab[tid*ESTR + s] = v[s] * im;
    etab[tid*ESTR + 24] = logf(m);
    etab[tid*ESTR + 25] = 0.f; etab[tid*ESTR + 26] = 0.f; etab[tid*ESTR + 27] = 0.f;
  }

  if (tid == 0) {
    float w[10];
    for (int q = 0; q < 10; ++q) w[q] = wt[q];
    float la[35];
    float d2 = 1.f - w[9]*w[9];
    float d3 = 1.f - w[9]*w[9]*w[9];
    la[0]=1.f-w[0]; la[1]=w[0];
    la[2]=1.f; la[3]=1.f;
    la[4]=w[1]; la[5]=w[3]; la[6]=d2; la[7]=d3;
    la[8]=1.f; la[9]=1.f;
    la[10]=w[2]; la[11]=w[4]; la[12]=d2;
    la[13]=1.f; la[14]=1.f;
    la[15]=1.f-w[5]; la[16]=w[5];
    la[17]=1.f; la[18]=1.f; la[19]=1.f;
    la[20]=1.f; la[21]=1.f;
    la[22]=1.f; la[23]=1.f;
    la[24]=w[6]; la[25]=1.f-w[6];
    la[26]=1.f; la[27]=1.f;
    la[28]=w[7]; la[29]=1.f-w[7];
    la[30]=1.f; la[31]=1.f;
    la[32]=w[8]; la[33]=1.f-w[8];
    la[34]=1.f;
    const int rs[25] = {0,2,3,4,8,9,10,13,14,15,17,18,19,20,22,23,24,26,27,28,30,31,32,34,35};
    for (int r = 0; r < 24; ++r) {
      float mx = -1e30f;
      for (int e = rs[r]; e < rs[r+1]; ++e) mx = fmaxf(mx, la[e]);
      float sm = 0.f;
      for (int e = rs[r]; e < rs[r+1]; ++e) sm += expf(la[e] - mx);
      float inv = 1.0f / sm;
      for (int e = rs[r]; e < rs[r+1]; ++e) a35out[e] = expf(la[e] - mx) * inv;
    }
  }
}

// ------------------------------------------------------------------
__global__ __launch_bounds__(256) void k_build_ctx(
    const int* __restrict__ obs, unsigned char* __restrict__ ctx8)
{
  int i = (int)blockIdx.x * 256 + (int)threadIdx.x;
  int t = i & (TLEN - 1);
  int o0 = obs[i];
  int o1 = (t >= 1) ? obs[i-1] : 4;
  int o2 = (t >= 2) ? obs[i-2] : 4;
  ctx8[i] = (unsigned char)((o2*5 + o1)*4 + o0);
}

// ------------------------------------------------------------------
// Phase A: thread = (chunk, batch, 4 columns). Carries 4 columns of the
// chunk transfer matrix; E-table LDS reads amortized 4x. Columns are
// max-renormalized every 16 steps AND at store (bf16 M, max entry = 1).
// ------------------------------------------------------------------
template<int C>
__global__ __launch_bounds__(256) void k_phaseA(
    const unsigned char* __restrict__ ctx8,
    const float* __restrict__ etab,
    const float* __restrict__ a35,
    unsigned short* __restrict__ M,
    float* __restrict__ lsbuf,
    float* __restrict__ csb)
{
  constexpr int BPC = (BATCH * 6) / 256;   // 12 blocks per chunk
  __shared__ __align__(16) float et[NCTX * ESTR];
  for (int i = threadIdx.x; i < NCTX * ESTR; i += 256) et[i] = etab[i];
  float A[35];
  #pragma unroll
  for (int e = 0; e < 35; ++e) A[e] = a35[e];
  __syncthreads();

  const int L = TLEN / C;
  int c    = (int)blockIdx.x / BPC;
  int il   = ((int)blockIdx.x % BPC) * 256 + (int)threadIdx.x;  // 0..3071
  int b    = il / 6;
  int q    = il % 6;
  int col0 = q * 4;

  float m[4][NST];
  #pragma unroll
  for (int u = 0; u < 4; ++u)
    #pragma unroll
    for (int s = 0; s < NST; ++s) m[u][s] = (s == col0 + u) ? 1.0f : 0.0f;

  const unsigned char* cb = ctx8 + (size_t)b * TLEN;
  float ls = 0.0f;
  float lsc[4] = {0.f, 0.f, 0.f, 0.f};
  int tstart = c * L;
  int nst = L;
  if (c == 0) {
    int ctx0 = cb[0];
    ls = logf(et[ctx0*ESTR]) + et[ctx0*ESTR + 24];   // ll0 = log B[0,4,4,obs0]
    tstart = 1; nst = L - 1;
  }

  const float4* etb = (const float4*)et;
  for (int k = 0; k < nst; ++k) {
    int ctx = cb[tstart + k];
    const float4* ep = etb + ctx * 7;
    float ev[NST];
    #pragma unroll
    for (int j = 0; j < 6; ++j) {
      float4 p = ep[j];
      ev[4*j] = p.x; ev[4*j+1] = p.y; ev[4*j+2] = p.z; ev[4*j+3] = p.w;
    }
    ls += et[ctx*ESTR + 24];
    #pragma unroll
    for (int u = 0; u < 4; ++u) {
      float R[NST];
      at_update(A, m[u], R);
      #pragma unroll
      for (int s = 0; s < NST; ++s) m[u][s] = R[s] * ev[s];
    }
    if ((k & 15) == 15 && k + 1 < nst) {
      #pragma unroll
      for (int u = 0; u < 4; ++u) {
        float cmax = 0.f;
        #pragma unroll
        for (int s = 0; s < NST; ++s) cmax = fmaxf(cmax, m[u][s]);
        if (cmax > 1e-35f) {
          float r = 1.0f / cmax;
          lsc[u] += logf(cmax);
          #pragma unroll
          for (int s = 0; s < NST; ++s) m[u][s] *= r;
        } else {
          lsc[u] = -1e30f;
          #pragma unroll
          for (int s = 0; s < NST; ++s) m[u][s] = 0.f;
        }
      }
    }
  }

  // final renorm (max entry of each stored column = 1 -> best bf16 precision)
  #pragma unroll
  for (int u = 0; u < 4; ++u) {
    float cmax = 0.f;
    #pragma unroll
    for (int s = 0; s < NST; ++s) cmax = fmaxf(cmax, m[u][s]);
    if (cmax > 1e-35f) {
      float r = 1.0f / cmax;
      lsc[u] += logf(cmax);
      #pragma unroll
      for (int s = 0; s < NST; ++s) m[u][s] *= r;
    } else {
      lsc[u] = -1e30f;
      #pragma unroll
      for (int s = 0; s < NST; ++s) m[u][s] = 0.f;
    }
  }

  size_t base = ((size_t)(c*BATCH + b)) * (NST*NST);
  #pragma unroll
  for (int s = 0; s < NST; ++s) {
    ushort4 w;
    w.x = f2bf(m[0][s]); w.y = f2bf(m[1][s]);
    w.z = f2bf(m[2][s]); w.w = f2bf(m[3][s]);
    *(ushort4*)(M + base + s*NST + col0) = w;
  }
  float4 cw = make_float4(lsc[0], lsc[1], lsc[2], lsc[3]);
  *(float4*)(csb + (size_t)(c*BATCH + b)*NST + col0) = cw;
  if (q == 0) lsbuf[c*BATCH + b] = ls;
}

// ------------------------------------------------------------------
// Phase B: sequential scan over chunks; 32-lane group per batch element.
// Next chunk's M rows are prefetched into registers during compute.
// ------------------------------------------------------------------
template<int C>
__global__ __launch_bounds__(256) void k_phaseB(
    const unsigned short* __restrict__ M,
    const float* __restrict__ lsbuf,
    const float* __restrict__ csb,
    float* __restrict__ vb,
    float* __restrict__ alphas,
    float* __restrict__ llout)
{
  int i = (int)blockIdx.x * 256 + (int)threadIdx.x;
  int b = i >> 5;
  int g = i & 31;
  bool act = g < NST;

  float v[NST];
  #pragma unroll
  for (int j = 0; j < NST; ++j) v[j] = (j == 0) ? 1.0f : 0.0f;

  if (act) {
    vb[((size_t)b*C + 0)*NST + g] = (g == 0) ? 1.0f : 0.0f;
    alphas[(size_t)b*TLEN*NST + g] = (g == 0) ? 1.0f : 0.0f;   // t = 0 row
  }

  uint4 a0, a1, a2; float csA, lsA;
  a0 = a1 = a2 = make_uint4(0,0,0,0); csA = -1e30f; lsA = 0.f;
  {
    if (act) {
      const uint4* p = (const uint4*)(M + (((size_t)b)*NST + g)*NST);
      a0 = p[0]; a1 = p[1]; a2 = p[2];
      csA = csb[(size_t)b*NST + g];
    }
    lsA = lsbuf[b];
  }

  float ll = 0.0f;
  for (int c = 0; c < C; ++c) {
    uint4 n0, n1, n2; float csN = -1e30f, lsN = 0.f;
    n0 = n1 = n2 = make_uint4(0,0,0,0);
    if (c + 1 < C) {                       // prefetch next chunk
      if (act) {
        const uint4* p = (const uint4*)(M + (((size_t)((c+1)*BATCH + b))*NST + g)*NST);
        n0 = p[0]; n1 = p[1]; n2 = p[2];
        csN = csb[(size_t)((c+1)*BATCH + b)*NST + g];
      }
      lsN = lsbuf[(c+1)*BATCH + b];
    }

    float mr[NST];
    {
      unsigned uu[12] = {a0.x,a0.y,a0.z,a0.w, a1.x,a1.y,a1.z,a1.w, a2.x,a2.y,a2.z,a2.w};
      #pragma unroll
      for (int j = 0; j < 12; ++j) {
        mr[2*j]   = __uint_as_float(uu[j] << 16);
        mr[2*j+1] = __uint_as_float(uu[j] & 0xFFFF0000u);
      }
    }

    // column scales: csm = max over active lanes; p_j = v_j * exp(cs_j - csm)
    float csm = csA;
    #pragma unroll
    for (int o = 1; o < 32; o <<= 1) csm = fmaxf(csm, __shfl_xor(csm, o, 32));
    float vg = act ? v[g] : 0.f;
    float pg = vg * expf(csA - csm);

    float p[NST];
    #pragma unroll
    for (int j = 0; j < NST; ++j) p[j] = __shfl(pg, j, 32);

    float nv = 0.f;
    #pragma unroll
    for (int j = 0; j < NST; ++j) nv += mr[j] * p[j];
    if (!act) nv = 0.f;

    float z = nv;
    #pragma unroll
    for (int o = 1; o < 32; o <<= 1) z += __shfl_xor(z, o, 32);

    float fn = nv / z;
    ll += logf(z) + csm + lsA;

    #pragma unroll
    for (int j = 0; j < NST; ++j) v[j] = __shfl(fn, j, 32);

    if (act && c + 1 < C) vb[((size_t)b*C + c + 1)*NST + g] = fn;

    a0 = n0; a1 = n1; a2 = n2; csA = csN; lsA = lsN;
  }
  if (g == 0) llout[b] = ll;
}

// ------------------------------------------------------------------
// Phase C: replay normalized vector recurrence inside each chunk, stream alphas.
// ------------------------------------------------------------------
template<int C>
__global__ __launch_bounds__(256) void k_phaseC(
    const unsigned char* __restrict__ ctx8,
    const float* __restrict__ etab,
    const float* __restrict__ a35,
    const float* __restrict__ vb,
    float* __restrict__ alphas)
{
  __shared__ __align__(16) float et[NCTX * ESTR];
  for (int i = threadIdx.x; i < NCTX * ESTR; i += 256) et[i] = etab[i];
  float A[35];
  #pragma unroll
  for (int e = 0; e < 35; ++e) A[e] = a35[e];
  __syncthreads();

  const int L = TLEN / C;
  int i = (int)blockIdx.x * 256 + (int)threadIdx.x;
  int b = i / C;
  int c = i % C;

  float f[NST];
  {
    const float4* p = (const float4*)(vb + ((size_t)b*C + c) * NST);
    #pragma unroll
    for (int j = 0; j < 6; ++j) {
      float4 q = p[j];
      f[4*j] = q.x; f[4*j+1] = q.y; f[4*j+2] = q.z; f[4*j+3] = q.w;
    }
  }

  const unsigned char* cb = ctx8 + (size_t)b * TLEN;
  const float4* etb = (const float4*)et;
  int t0 = c * L;
  for (int k = 0; k < L; ++k) {
    int t = t0 + k;
    if (t == 0) continue;      // t=0 row written by phase B
    int ctx = cb[t];
    const float4* ep = etb + ctx * 7;
    float ev[NST];
    #pragma unroll
    for (int j = 0; j < 6; ++j) {
      float4 q = ep[j];
      ev[4*j] = q.x; ev[4*j+1] = q.y; ev[4*j+2] = q.z; ev[4*j+3] = q.w;
    }
    float R[NST];
    at_update(A, f, R);
    float al[NST];
    #pragma unroll
    for (int s = 0; s < NST; ++s) al[s] = R[s] * ev[s];
    float z = tree_sum24(al);
    float zr = 1.0f / z;
    #pragma unroll
    for (int s = 0; s < NST; ++s) f[s] = al[s] * zr;

    float* op = alphas + ((size_t)b*TLEN + t) * NST;
    float4* o4 = (float4*)op;
    o4[0] = make_float4(f[0],  f[1],  f[2],  f[3]);
    o4[1] = make_float4(f[4],  f[5],  f[6],  f[7]);
    o4[2] = make_float4(f[8],  f[9],  f[10], f[11]);
    o4[3] = make_float4(f[12], f[13], f[14], f[15]);
    o4[4] = make_float4(f[16], f[17], f[18], f[19]);
    o4[5] = make_float4(f[20], f[21], f[22], f[23]);
  }
}

// ------------------------------------------------------------------
template<int C>
static void run_pipeline(const unsigned char* ctx8, const float* etab, const float* a35,
                         unsigned short* mbuf, float* lsb, float* csb, float* vb,
                         float* alphas, float* llout, hipStream_t stream)
{
  constexpr int BPC = (BATCH * 6) / 256;
  k_phaseA<C><<<C * BPC, 256, 0, stream>>>(ctx8, etab, a35, mbuf, lsb, csb);
  k_phaseB<C><<<(BATCH * 32) / 256, 256, 0, stream>>>(mbuf, lsb, csb, vb, alphas, llout);
  k_phaseC<C><<<(BATCH * C) / 256, 256, 0, stream>>>(ctx8, etab, a35, vb, alphas);
}

extern "C" void kernel_launch(void* const* d_in, const int* in_sizes, int n_in,
                              void* d_out, int out_size, void* d_ws, size_t ws_size,
                              hipStream_t stream)
{
  (void)in_sizes; (void)n_in; (void)out_size;
  const int*   obs = (const int*)d_in[0];
  const float* wt  = (const float*)d_in[1];
  const float* we  = (const float*)d_in[2];
  // d_in[3] (init_kernel) is mathematically unused: softmax of 1 element == 1.

  float* out    = (float*)d_out;
  float* alphas = out;
  float* llout  = out + (size_t)BATCH * TLEN * NST;

  char* ws = (char*)d_ws;
  const size_t ETAB_OFF = 0;                                        // 11200 B
  const size_t A_OFF    = 12 * 1024;
  const size_t CTX_OFF  = 16 * 1024;                                // 1 MiB
  const size_t LS_OFF   = CTX_OFF + (size_t)BATCH * TLEN;           // MAXC*512*4
  const size_t CS_OFF   = LS_OFF + (size_t)MAXC * BATCH * 4;        // MAXC*512*24*4
  const size_t VB_OFF   = CS_OFF + (size_t)MAXC * BATCH * NST * 4;  // 512*MAXC*24*4
  const size_t M_OFF    = VB_OFF + (size_t)BATCH * MAXC * NST * 4;

  float* etab = (float*)(ws + ETAB_OFF);
  float* a35  = (float*)(ws + A_OFF);
  unsigned char* ctx8 = (unsigned char*)(ws + CTX_OFF);
  float* lsb  = (float*)(ws + LS_OFF);
  float* csb  = (float*)(ws + CS_OFF);
  float* vb   = (float*)(ws + VB_OFF);
  unsigned short* mbuf = (unsigned short*)(ws + M_OFF);

  k_build_tables<<<1, 256, 0, stream>>>(wt, we, etab, a35);
  k_build_ctx<<<(BATCH * TLEN) / 256, 256, 0, stream>>>(obs, ctx8);

  const size_t need128 = M_OFF + (size_t)128 * BATCH * NST * NST * 2;
  const size_t need32  = M_OFF + (size_t)32  * BATCH * NST * NST * 2;

  if (ws_size >= need128) {
    run_pipeline<128>(ctx8, etab, a35, mbuf, lsb, csb, vb, alphas, llout, stream);
  } else if (ws_size >= need32) {
    run_pipeline<32>(ctx8, etab, a35, mbuf, lsb, csb, vb, alphas, llout, stream);
  } else {
    run_pipeline<8>(ctx8, etab, a35, mbuf, lsb, csb, vb, alphas, llout, stream);
  }
}

// Round 4
// 226.190 us; speedup vs baseline: 1.4598x; 1.4598x over previous
//
#include <hip/hip_runtime.h>

#define BATCH 512
#define TLEN  2048
#define NST   24
#define ESTR  28          // floats per ctx row in E table: 24 E + lognorm + 3 pad
#define NCTX  100         // ctx = (c2*5 + c1)*4 + c0  (c2,c1 in 0..4, c0 in 0..3)
#define CB    32          // coarse chunks (phase A matrices, phase B scan length)
#define CF    128         // fine chunks (phase C parallelism)
#define FPC   (CF/CB)     // fine per coarse = 4

__device__ __forceinline__ unsigned short f2bf(float x) {
  unsigned u = __float_as_uint(x);
  u += 0x7FFFu + ((u >> 16) & 1u);
  return (unsigned short)(u >> 16);
}

// R[dst] = sum over edges (src->dst) of A[edge]*f[src]; edges numbered source-major.
__device__ __forceinline__ void at_update(const float* __restrict__ A,
                                          const float* __restrict__ f,
                                          float* __restrict__ R) {
  R[0]  = A[0]*f[0];
  R[1]  = A[1]*f[0];
  R[2]  = A[2]*f[1];
  R[3]  = A[3]*f[2];
  R[4]  = A[4]*f[3]  + A[24]*f[16];
  R[5]  = A[8]*f[4];
  R[6]  = A[9]*f[5];
  R[7]  = A[6]*f[3]  + A[10]*f[6] + A[28]*f[19];
  R[8]  = A[13]*f[7];
  R[9]  = A[14]*f[8];
  R[10] = A[7]*f[3]  + A[12]*f[6] + A[15]*f[9] + A[32]*f[22];
  R[11] = A[17]*f[10];
  R[12] = A[18]*f[11];
  R[13] = A[19]*f[12] + A[20]*f[13];
  R[14] = A[5]*f[3]  + A[25]*f[16];
  R[15] = A[22]*f[14];
  R[16] = A[23]*f[15];
  R[17] = A[11]*f[6] + A[29]*f[19];
  R[18] = A[26]*f[17];
  R[19] = A[27]*f[18];
  R[20] = A[16]*f[9] + A[33]*f[22];
  R[21] = A[30]*f[20];
  R[22] = A[31]*f[21];
  R[23] = A[21]*f[13] + A[34]*f[23];
}

__device__ __forceinline__ float tree_sum24(const float* a) {
  float s0 = a[0]+a[1],   s1 = a[2]+a[3],   s2 = a[4]+a[5],   s3 = a[6]+a[7];
  float s4 = a[8]+a[9],   s5 = a[10]+a[11], s6 = a[12]+a[13], s7 = a[14]+a[15];
  float s8 = a[16]+a[17], s9 = a[18]+a[19], s10= a[20]+a[21], s11= a[22]+a[23];
  float u0 = s0+s1, u1 = s2+s3, u2 = s4+s5, u3 = s6+s7, u4 = s8+s9, u5 = s10+s11;
  return ((u0+u1) + (u2+u3)) + (u4+u5);
}

// one normalized vector step: f <- normalize((A^T f) * ev)
__device__ __forceinline__ void vec_step(const float* __restrict__ A,
                                         const float* __restrict__ ev,
                                         float* __restrict__ f) {
  float R[NST];
  at_update(A, f, R);
  float al[NST];
  #pragma unroll
  for (int s = 0; s < NST; ++s) al[s] = R[s] * ev[s];
  float z = tree_sum24(al);
  float zr = 1.0f / z;
  #pragma unroll
  for (int s = 0; s < NST; ++s) f[s] = al[s] * zr;
}

__device__ __forceinline__ void load_ev(const float4* __restrict__ etb, int ctx,
                                        float* __restrict__ ev) {
  const float4* ep = etb + ctx * 7;
  #pragma unroll
  for (int j = 0; j < 6; ++j) {
    float4 q = ep[j];
    ev[4*j] = q.x; ev[4*j+1] = q.y; ev[4*j+2] = q.z; ev[4*j+3] = q.w;
  }
}

// ------------------------------------------------------------------
// Builder: A edge values (row softmax) + normalized E table per context.
// ------------------------------------------------------------------
__global__ __launch_bounds__(256) void k_build_tables(
    const float* __restrict__ wt, const float* __restrict__ we,
    float* __restrict__ etab, float* __restrict__ a35out)
{
  __shared__ float lg[NST * 216];
  __shared__ float rmx[NST];
  __shared__ float rrs[NST];
  int tid = threadIdx.x;
  for (int i = tid; i < NST * 216; i += 256) lg[i] = -1e30f;
  __syncthreads();

  for (int e = tid; e < 1073; e += 256) {
    int s, i, j, l, k = -1;
    if (e < 84)        { int ep=e; l=ep&3; int p=ep>>2; if (p<16){i=p>>2;j=p&3;} else {i=4;j=p-16;} s=0; k=ep; }
    else if (e < 104)  { int ep=e-84;  s=1;  i=ep>>2; j=ep&3; l=0; k=84+ep; }
    else if (e < 108)  { int ep=e-104; s=2;  i=ep;    j=0;    l=3; k=104+ep; }
    else if (e < 109)  { s=3; i=0; j=3; l=2; }
    else if (e < 113)  { int ep=e-109; s=4;  i=3; j=2; l=ep;  k=108+ep; }
    else if (e < 129)  { int ep=e-113; s=5;  i=2; j=ep>>2; l=ep&3; k=112+ep; }
    else if (e < 385)  { int ep=e-129; s=6+(ep>>6); int q=ep&63; i=q>>4; j=(q>>2)&3; l=q&3; k=128+ep; }
    else if (e < 401)  { int ep=e-385; s=10; i=ep>>2; j=ep&3; l=3; k=384+ep; }
    else if (e < 405)  { int ep=e-401; s=11; i=ep; j=3; l=0; k=400+ep; }
    else if (e < 409)  { int ep=e-405; s=11; i=ep; j=3; l=2; k=404+ep; }
    else if (e < 412)  { int ep=e-409; s=12; i=3; j=(ep==2)?2:0; l=(ep==1)?2:0; }
    else if (e < 476)  { int ep=e-412; s=13; i=ep>>4; j=(ep>>2)&3; l=ep&3; k=408+ep; }
    else if (e < 1052) { int ep=e-476; s=14+(ep>>6); int q=ep&63; i=q>>4; j=(q>>2)&3; l=q&3; k=472+ep; }
    else if (e < 1068) { int ep=e-1052; s=23; i=ep>>2; j=ep&3; l=5; k=1048+ep; }
    else if (e < 1072) { int ep=e-1068; s=23; i=ep; j=5; l=5; k=1064+ep; }
    else               { s=23; i=5; j=5; l=5; }
    float v = (k < 0) ? 1.0f : we[k];
    lg[s*216 + i*36 + j*6 + l] = v;
  }
  __syncthreads();

  if (tid < NST) {
    float mx = -1e30f;
    for (int x = 0; x < 216; ++x) mx = fmaxf(mx, lg[tid*216 + x]);
    float sum = 0.f;
    for (int x = 0; x < 216; ++x) sum += expf(lg[tid*216 + x] - mx);
    rmx[tid] = mx;
    rrs[tid] = 1.0f / sum;
  }
  __syncthreads();

  if (tid < NCTX) {
    int c2 = tid / 20, c1 = (tid >> 2) % 5, c0 = tid & 3;
    int x = c2*36 + c1*6 + c0;
    float v[NST];
    float m = 1e-30f;
    for (int s = 0; s < NST; ++s) {
      v[s] = expf(lg[s*216 + x] - rmx[s]) * rrs[s];
      m = fmaxf(m, v[s]);
    }
    float im = 1.0f / m;
    for (int s = 0; s < NST; ++s) etab[tid*ESTR + s] = v[s] * im;
    etab[tid*ESTR + 24] = logf(m);
    etab[tid*ESTR + 25] = 0.f; etab[tid*ESTR + 26] = 0.f; etab[tid*ESTR + 27] = 0.f;
  }

  if (tid == 0) {
    float w[10];
    for (int q = 0; q < 10; ++q) w[q] = wt[q];
    float la[35];
    float d2 = 1.f - w[9]*w[9];
    float d3 = 1.f - w[9]*w[9]*w[9];
    la[0]=1.f-w[0]; la[1]=w[0];
    la[2]=1.f; la[3]=1.f;
    la[4]=w[1]; la[5]=w[3]; la[6]=d2; la[7]=d3;
    la[8]=1.f; la[9]=1.f;
    la[10]=w[2]; la[11]=w[4]; la[12]=d2;
    la[13]=1.f; la[14]=1.f;
    la[15]=1.f-w[5]; la[16]=w[5];
    la[17]=1.f; la[18]=1.f; la[19]=1.f;
    la[20]=1.f; la[21]=1.f;
    la[22]=1.f; la[23]=1.f;
    la[24]=w[6]; la[25]=1.f-w[6];
    la[26]=1.f; la[27]=1.f;
    la[28]=w[7]; la[29]=1.f-w[7];
    la[30]=1.f; la[31]=1.f;
    la[32]=w[8]; la[33]=1.f-w[8];
    la[34]=1.f;
    const int rs[25] = {0,2,3,4,8,9,10,13,14,15,17,18,19,20,22,23,24,26,27,28,30,31,32,34,35};
    for (int r = 0; r < 24; ++r) {
      float mx = -1e30f;
      for (int e = rs[r]; e < rs[r+1]; ++e) mx = fmaxf(mx, la[e]);
      float sm = 0.f;
      for (int e = rs[r]; e < rs[r+1]; ++e) sm += expf(la[e] - mx);
      float inv = 1.0f / sm;
      for (int e = rs[r]; e < rs[r+1]; ++e) a35out[e] = expf(la[e] - mx) * inv;
    }
  }
}

// ------------------------------------------------------------------
__global__ __launch_bounds__(256) void k_build_ctx(
    const int* __restrict__ obs, unsigned char* __restrict__ ctx8)
{
  int i = (int)blockIdx.x * 256 + (int)threadIdx.x;
  int t = i & (TLEN - 1);
  int o0 = obs[i];
  int o1 = (t >= 1) ? obs[i-1] : 4;
  int o2 = (t >= 2) ? obs[i-2] : 4;
  ctx8[i] = (unsigned char)((o2*5 + o1)*4 + o0);
}

// ------------------------------------------------------------------
// Phase A (coarse C=CB): thread = (chunk, batch, 4 columns) of the chunk
// transfer matrix; renormalized every 16 steps and at store (bf16 M).
// ------------------------------------------------------------------
__global__ __launch_bounds__(256) void k_phaseA(
    const unsigned char* __restrict__ ctx8,
    const float* __restrict__ etab,
    const float* __restrict__ a35,
    unsigned short* __restrict__ M,
    float* __restrict__ lsbuf,
    float* __restrict__ csb)
{
  constexpr int BPC = (BATCH * 6) / 256;   // 12 blocks per chunk
  __shared__ __align__(16) float et[NCTX * ESTR];
  for (int i = threadIdx.x; i < NCTX * ESTR; i += 256) et[i] = etab[i];
  float A[35];
  #pragma unroll
  for (int e = 0; e < 35; ++e) A[e] = a35[e];
  __syncthreads();

  const int L = TLEN / CB;                 // 64
  int c    = (int)blockIdx.x / BPC;
  int il   = ((int)blockIdx.x % BPC) * 256 + (int)threadIdx.x;  // 0..3071
  int b    = il / 6;
  int q    = il % 6;
  int col0 = q * 4;

  float m[4][NST];
  #pragma unroll
  for (int u = 0; u < 4; ++u)
    #pragma unroll
    for (int s = 0; s < NST; ++s) m[u][s] = (s == col0 + u) ? 1.0f : 0.0f;

  const unsigned char* cb = ctx8 + (size_t)b * TLEN;
  float ls = 0.0f;
  float lsc[4] = {0.f, 0.f, 0.f, 0.f};
  int tstart = c * L;
  int nst = L;
  if (c == 0) {
    int ctx0 = cb[0];
    ls = logf(et[ctx0*ESTR]) + et[ctx0*ESTR + 24];   // ll0 = log B[0,4,4,obs0]
    tstart = 1; nst = L - 1;
  }

  const float4* etb = (const float4*)et;
  for (int k = 0; k < nst; ++k) {
    int ctx = cb[tstart + k];
    float ev[NST];
    load_ev(etb, ctx, ev);
    ls += et[ctx*ESTR + 24];
    #pragma unroll
    for (int u = 0; u < 4; ++u) {
      float R[NST];
      at_update(A, m[u], R);
      #pragma unroll
      for (int s = 0; s < NST; ++s) m[u][s] = R[s] * ev[s];
    }
    if ((k & 15) == 15 && k + 1 < nst) {
      #pragma unroll
      for (int u = 0; u < 4; ++u) {
        float cmax = 0.f;
        #pragma unroll
        for (int s = 0; s < NST; ++s) cmax = fmaxf(cmax, m[u][s]);
        if (cmax > 1e-35f) {
          float r = 1.0f / cmax;
          lsc[u] += logf(cmax);
          #pragma unroll
          for (int s = 0; s < NST; ++s) m[u][s] *= r;
        } else {
          lsc[u] = -1e30f;
          #pragma unroll
          for (int s = 0; s < NST; ++s) m[u][s] = 0.f;
        }
      }
    }
  }

  // final renorm (max entry of each stored column = 1 -> best bf16 precision)
  #pragma unroll
  for (int u = 0; u < 4; ++u) {
    float cmax = 0.f;
    #pragma unroll
    for (int s = 0; s < NST; ++s) cmax = fmaxf(cmax, m[u][s]);
    if (cmax > 1e-35f) {
      float r = 1.0f / cmax;
      lsc[u] += logf(cmax);
      #pragma unroll
      for (int s = 0; s < NST; ++s) m[u][s] *= r;
    } else {
      lsc[u] = -1e30f;
      #pragma unroll
      for (int s = 0; s < NST; ++s) m[u][s] = 0.f;
    }
  }

  size_t base = ((size_t)(c*BATCH + b)) * (NST*NST);
  #pragma unroll
  for (int s = 0; s < NST; ++s) {
    ushort4 w;
    w.x = f2bf(m[0][s]); w.y = f2bf(m[1][s]);
    w.z = f2bf(m[2][s]); w.w = f2bf(m[3][s]);
    *(ushort4*)(M + base + s*NST + col0) = w;
  }
  float4 cw = make_float4(lsc[0], lsc[1], lsc[2], lsc[3]);
  *(float4*)(csb + (size_t)(c*BATCH + b)*NST + col0) = cw;
  if (q == 0) lsbuf[c*BATCH + b] = ls;
}

// ------------------------------------------------------------------
// Phase B: scan over CB coarse chunks. Block = 1 wave = 2 batches
// (32 lanes each). Every lane holds the FULL v[24] and cs[24] replicated;
// the matvec is entirely in-lane; only z needs a cross-lane reduce; the
// fn -> v transpose goes through one LDS write + float4 reads.
// ------------------------------------------------------------------
__global__ __launch_bounds__(64) void k_phaseB(
    const unsigned short* __restrict__ M,
    const float* __restrict__ lsbuf,
    const float* __restrict__ csb,
    float* __restrict__ vbc,
    float* __restrict__ alphas,
    float* __restrict__ llout)
{
  __shared__ __align__(16) float xfer[64];
  int lane = (int)threadIdx.x;
  int sub  = lane >> 5;
  int g    = lane & 31;
  bool act = g < NST;
  int gi   = act ? g : 0;
  int b    = (int)blockIdx.x * 2 + sub;

  float v[NST];
  #pragma unroll
  for (int j = 0; j < NST; ++j) v[j] = (j == 0) ? 1.0f : 0.0f;

  if (act) {
    vbc[((size_t)b*CB + 0)*NST + g] = (g == 0) ? 1.0f : 0.0f;
    alphas[(size_t)b*TLEN*NST + g]  = (g == 0) ? 1.0f : 0.0f;   // t = 0 row
  }

  // current chunk (c=0) loads
  uint4  cM0, cM1, cM2;
  float4 cS0, cS1, cS2, cS3, cS4, cS5;
  float  cLS;
  {
    const uint4* p = (const uint4*)(M + (((size_t)b)*NST + gi)*NST);
    cM0 = p[0]; cM1 = p[1]; cM2 = p[2];
    const float4* s = (const float4*)(csb + (size_t)b*NST);
    cS0 = s[0]; cS1 = s[1]; cS2 = s[2]; cS3 = s[3]; cS4 = s[4]; cS5 = s[5];
    cLS = lsbuf[b];
  }

  float ll = 0.0f;
  for (int c = 0; c < CB; ++c) {
    uint4  nM0, nM1, nM2;
    float4 nS0, nS1, nS2, nS3, nS4, nS5;
    float  nLS = 0.f;
    nM0 = nM1 = nM2 = make_uint4(0,0,0,0);
    nS0 = nS1 = nS2 = nS3 = nS4 = nS5 = make_float4(-1e30f,-1e30f,-1e30f,-1e30f);
    if (c + 1 < CB) {
      const uint4* p = (const uint4*)(M + (((size_t)((c+1)*BATCH + b))*NST + gi)*NST);
      nM0 = p[0]; nM1 = p[1]; nM2 = p[2];
      const float4* s = (const float4*)(csb + (size_t)((c+1)*BATCH + b)*NST);
      nS0 = s[0]; nS1 = s[1]; nS2 = s[2]; nS3 = s[3]; nS4 = s[4]; nS5 = s[5];
      nLS = lsbuf[(c+1)*BATCH + b];
    }

    float cs[NST];
    cs[0]=cS0.x; cs[1]=cS0.y; cs[2]=cS0.z; cs[3]=cS0.w;
    cs[4]=cS1.x; cs[5]=cS1.y; cs[6]=cS1.z; cs[7]=cS1.w;
    cs[8]=cS2.x; cs[9]=cS2.y; cs[10]=cS2.z; cs[11]=cS2.w;
    cs[12]=cS3.x; cs[13]=cS3.y; cs[14]=cS3.z; cs[15]=cS3.w;
    cs[16]=cS4.x; cs[17]=cS4.y; cs[18]=cS4.z; cs[19]=cS4.w;
    cs[20]=cS5.x; cs[21]=cS5.y; cs[22]=cS5.z; cs[23]=cS5.w;

    // csm = max_j cs[j] (in-register tree)
    float csm = cs[0];
    #pragma unroll
    for (int j = 1; j < NST; ++j) csm = fmaxf(csm, cs[j]);

    // p[j] = v[j]*exp(cs[j]-csm)
    float p[NST];
    #pragma unroll
    for (int j = 0; j < NST; ++j) p[j] = v[j] * __expf(cs[j] - csm);

    // unpack this lane's M row (bf16 -> f32)
    float mr[NST];
    {
      unsigned uu[12] = {cM0.x,cM0.y,cM0.z,cM0.w, cM1.x,cM1.y,cM1.z,cM1.w,
                         cM2.x,cM2.y,cM2.z,cM2.w};
      #pragma unroll
      for (int j = 0; j < 12; ++j) {
        mr[2*j]   = __uint_as_float(uu[j] << 16);
        mr[2*j+1] = __uint_as_float(uu[j] & 0xFFFF0000u);
      }
    }

    float pr[NST];
    #pragma unroll
    for (int j = 0; j < NST; ++j) pr[j] = mr[j] * p[j];
    float nv = act ? tree_sum24(pr) : 0.f;

    float z = nv;
    #pragma unroll
    for (int o = 1; o < 32; o <<= 1) z += __shfl_xor(z, o, 32);

    float fn = nv / z;
    ll += __logf(z) + csm + cLS;

    if (act && c + 1 < CB) vbc[((size_t)b*CB + c + 1)*NST + g] = fn;

    // transpose fn -> replicated v via LDS
    xfer[sub*32 + g] = fn;
    __syncthreads();
    {
      const float4* x4 = (const float4*)(&xfer[sub*32]);
      float4 q0 = x4[0], q1 = x4[1], q2 = x4[2],
             q3 = x4[3], q4 = x4[4], q5 = x4[5];
      v[0]=q0.x; v[1]=q0.y; v[2]=q0.z; v[3]=q0.w;
      v[4]=q1.x; v[5]=q1.y; v[6]=q1.z; v[7]=q1.w;
      v[8]=q2.x; v[9]=q2.y; v[10]=q2.z; v[11]=q2.w;
      v[12]=q3.x; v[13]=q3.y; v[14]=q3.z; v[15]=q3.w;
      v[16]=q4.x; v[17]=q4.y; v[18]=q4.z; v[19]=q4.w;
      v[20]=q5.x; v[21]=q5.y; v[22]=q5.z; v[23]=q5.w;
    }
    __syncthreads();

    cM0 = nM0; cM1 = nM1; cM2 = nM2;
    cS0 = nS0; cS1 = nS1; cS2 = nS2; cS3 = nS3; cS4 = nS4; cS5 = nS5;
    cLS = nLS;
  }
  if (g == 0) llout[b] = ll;
}

// ------------------------------------------------------------------
// Expand: one thread per (b, coarse chunk). Replays 48 vector steps to
// emit fine boundaries vbf[4g..4g+3] from the coarse boundary vbc[g].
// ------------------------------------------------------------------
__global__ __launch_bounds__(64) void k_expand(
    const unsigned char* __restrict__ ctx8,
    const float* __restrict__ etab,
    const float* __restrict__ a35,
    const float* __restrict__ vbc,
    float* __restrict__ vbf)
{
  __shared__ __align__(16) float et[NCTX * ESTR];
  for (int i = threadIdx.x; i < NCTX * ESTR; i += 64) et[i] = etab[i];
  float A[35];
  #pragma unroll
  for (int e = 0; e < 35; ++e) A[e] = a35[e];
  __syncthreads();

  int i = (int)blockIdx.x * 64 + (int)threadIdx.x;
  int b = i >> 5;          // / CB
  int g = i & 31;          // % CB

  float f[NST];
  {
    const float4* p = (const float4*)(vbc + ((size_t)b*CB + g) * NST);
    #pragma unroll
    for (int j = 0; j < 6; ++j) {
      float4 q = p[j];
      f[4*j] = q.x; f[4*j+1] = q.y; f[4*j+2] = q.z; f[4*j+3] = q.w;
    }
  }
  {
    float4* o = (float4*)(vbf + ((size_t)b*CF + g*FPC) * NST);
    o[0] = make_float4(f[0],f[1],f[2],f[3]);
    o[1] = make_float4(f[4],f[5],f[6],f[7]);
    o[2] = make_float4(f[8],f[9],f[10],f[11]);
    o[3] = make_float4(f[12],f[13],f[14],f[15]);
    o[4] = make_float4(f[16],f[17],f[18],f[19]);
    o[5] = make_float4(f[20],f[21],f[22],f[23]);
  }

  const unsigned char* cb = ctx8 + (size_t)b * TLEN;
  const float4* etb = (const float4*)et;
  int t = g * (TLEN / CB);
  #pragma unroll
  for (int k3 = 1; k3 < FPC; ++k3) {
    for (int k = 0; k < TLEN/CF; ++k) {
      if (t != 0) {
        int ctx = cb[t];
        float ev[NST];
        load_ev(etb, ctx, ev);
        vec_step(A, ev, f);
      }
      ++t;
    }
    float4* o = (float4*)(vbf + ((size_t)b*CF + g*FPC + k3) * NST);
    o[0] = make_float4(f[0],f[1],f[2],f[3]);
    o[1] = make_float4(f[4],f[5],f[6],f[7]);
    o[2] = make_float4(f[8],f[9],f[10],f[11]);
    o[3] = make_float4(f[12],f[13],f[14],f[15]);
    o[4] = make_float4(f[16],f[17],f[18],f[19]);
    o[5] = make_float4(f[20],f[21],f[22],f[23]);
  }
}

// ------------------------------------------------------------------
// Phase C (fine C=CF): replay the recurrence inside each fine chunk,
// stream alphas with float4 stores.
// ------------------------------------------------------------------
__global__ __launch_bounds__(256) void k_phaseC(
    const unsigned char* __restrict__ ctx8,
    const float* __restrict__ etab,
    const float* __restrict__ a35,
    const float* __restrict__ vbf,
    float* __restrict__ alphas)
{
  __shared__ __align__(16) float et[NCTX * ESTR];
  for (int i = threadIdx.x; i < NCTX * ESTR; i += 256) et[i] = etab[i];
  float A[35];
  #pragma unroll
  for (int e = 0; e < 35; ++e) A[e] = a35[e];
  __syncthreads();

  const int L = TLEN / CF;   // 16
  int i = (int)blockIdx.x * 256 + (int)threadIdx.x;
  int b = i / CF;
  int c = i % CF;

  float f[NST];
  {
    const float4* p = (const float4*)(vbf + ((size_t)b*CF + c) * NST);
    #pragma unroll
    for (int j = 0; j < 6; ++j) {
      float4 q = p[j];
      f[4*j] = q.x; f[4*j+1] = q.y; f[4*j+2] = q.z; f[4*j+3] = q.w;
    }
  }

  const unsigned char* cb = ctx8 + (size_t)b * TLEN;
  const float4* etb = (const float4*)et;
  int t0 = c * L;
  for (int k = 0; k < L; ++k) {
    int t = t0 + k;
    if (t == 0) continue;      // t=0 row written by phase B
    int ctx = cb[t];
    float ev[NST];
    load_ev(etb, ctx, ev);
    vec_step(A, ev, f);

    float4* o4 = (float4*)(alphas + ((size_t)b*TLEN + t) * NST);
    o4[0] = make_float4(f[0],  f[1],  f[2],  f[3]);
    o4[1] = make_float4(f[4],  f[5],  f[6],  f[7]);
    o4[2] = make_float4(f[8],  f[9],  f[10], f[11]);
    o4[3] = make_float4(f[12], f[13], f[14], f[15]);
    o4[4] = make_float4(f[16], f[17], f[18], f[19]);
    o4[5] = make_float4(f[20], f[21], f[22], f[23]);
  }
}

// ------------------------------------------------------------------
extern "C" void kernel_launch(void* const* d_in, const int* in_sizes, int n_in,
                              void* d_out, int out_size, void* d_ws, size_t ws_size,
                              hipStream_t stream)
{
  (void)in_sizes; (void)n_in; (void)out_size; (void)ws_size;
  const int*   obs = (const int*)d_in[0];
  const float* wt  = (const float*)d_in[1];
  const float* we  = (const float*)d_in[2];
  // d_in[3] (init_kernel) is mathematically unused: softmax of 1 element == 1.

  float* out    = (float*)d_out;
  float* alphas = out;
  float* llout  = out + (size_t)BATCH * TLEN * NST;

  char* ws = (char*)d_ws;
  const size_t ETAB_OFF = 0;                                        // 11200 B
  const size_t A_OFF    = 12 * 1024;
  const size_t CTX_OFF  = 16 * 1024;                                // 1 MiB
  const size_t LS_OFF   = CTX_OFF + (size_t)BATCH * TLEN;           // CB*512*4      = 64 KiB
  const size_t CS_OFF   = LS_OFF + (size_t)CB * BATCH * 4;          // CB*512*24*4   = 1.5 MiB
  const size_t VBC_OFF  = CS_OFF + (size_t)CB * BATCH * NST * 4;    // 512*CB*24*4   = 1.5 MiB
  const size_t VBF_OFF  = VBC_OFF + (size_t)BATCH * CB * NST * 4;   // 512*CF*24*4   = 6 MiB
  const size_t M_OFF    = VBF_OFF + (size_t)BATCH * CF * NST * 4;   // CB*512*576*2  = 18 MiB

  float* etab = (float*)(ws + ETAB_OFF);
  float* a35  = (float*)(ws + A_OFF);
  unsigned char* ctx8 = (unsigned char*)(ws + CTX_OFF);
  float* lsb  = (float*)(ws + LS_OFF);
  float* csb  = (float*)(ws + CS_OFF);
  float* vbc  = (float*)(ws + VBC_OFF);
  float* vbf  = (float*)(ws + VBF_OFF);
  unsigned short* mbuf = (unsigned short*)(ws + M_OFF);

  k_build_tables<<<1, 256, 0, stream>>>(wt, we, etab, a35);
  k_build_ctx<<<(BATCH * TLEN) / 256, 256, 0, stream>>>(obs, ctx8);
  k_phaseA<<<CB * ((BATCH * 6) / 256), 256, 0, stream>>>(ctx8, etab, a35, mbuf, lsb, csb);
  k_phaseB<<<BATCH / 2, 64, 0, stream>>>(mbuf, lsb, csb, vbc, alphas, llout);
  k_expand<<<(BATCH * CB) / 64, 64, 0, stream>>>(ctx8, etab, a35, vbc, vbf);
  k_phaseC<<<(BATCH * CF) / 256, 256, 0, stream>>>(ctx8, etab, a35, vbf, alphas);
}

// Round 5
// 219.492 us; speedup vs baseline: 1.5043x; 1.0305x over previous
//
#include <hip/hip_runtime.h>

#define BATCH 512
#define TLEN  2048
#define NST   24
#define ESTR  28          // floats per ctx row in E table: 24 E + lognorm + 3 pad
#define NCTX  100         // ctx = (c2*5 + c1)*4 + c0  (c2,c1 in 0..4, c0 in 0..3)
#define CF    256         // fine chunks (phase C parallelism), L_fine = 8

__device__ __forceinline__ unsigned short f2bf(float x) {
  unsigned u = __float_as_uint(x);
  u += 0x7FFFu + ((u >> 16) & 1u);
  return (unsigned short)(u >> 16);
}

__device__ __forceinline__ float sload(const float* p) {
  return __uint_as_float(__builtin_amdgcn_readfirstlane(__float_as_uint(*p)));
}

// R[dst] = sum over edges (src->dst) of A[edge]*f[src]; edges numbered source-major.
__device__ __forceinline__ void at_update(const float* __restrict__ A,
                                          const float* __restrict__ f,
                                          float* __restrict__ R) {
  R[0]  = A[0]*f[0];
  R[1]  = A[1]*f[0];
  R[2]  = A[2]*f[1];
  R[3]  = A[3]*f[2];
  R[4]  = A[4]*f[3]  + A[24]*f[16];
  R[5]  = A[8]*f[4];
  R[6]  = A[9]*f[5];
  R[7]  = A[6]*f[3]  + A[10]*f[6] + A[28]*f[19];
  R[8]  = A[13]*f[7];
  R[9]  = A[14]*f[8];
  R[10] = A[7]*f[3]  + A[12]*f[6] + A[15]*f[9] + A[32]*f[22];
  R[11] = A[17]*f[10];
  R[12] = A[18]*f[11];
  R[13] = A[19]*f[12] + A[20]*f[13];
  R[14] = A[5]*f[3]  + A[25]*f[16];
  R[15] = A[22]*f[14];
  R[16] = A[23]*f[15];
  R[17] = A[11]*f[6] + A[29]*f[19];
  R[18] = A[26]*f[17];
  R[19] = A[27]*f[18];
  R[20] = A[16]*f[9] + A[33]*f[22];
  R[21] = A[30]*f[20];
  R[22] = A[31]*f[21];
  R[23] = A[21]*f[13] + A[34]*f[23];
}

// scaled edges: As[e] = A[e]*ev[dst[e]] (35 mul, shared across a thread's columns)
__device__ __forceinline__ void scale_edges(const float* __restrict__ A,
                                            const float* __restrict__ ev,
                                            float* __restrict__ As) {
  As[0]=A[0]*ev[0];   As[1]=A[1]*ev[1];   As[2]=A[2]*ev[2];   As[3]=A[3]*ev[3];
  As[4]=A[4]*ev[4];   As[5]=A[5]*ev[14];  As[6]=A[6]*ev[7];   As[7]=A[7]*ev[10];
  As[8]=A[8]*ev[5];   As[9]=A[9]*ev[6];   As[10]=A[10]*ev[7]; As[11]=A[11]*ev[17];
  As[12]=A[12]*ev[10];As[13]=A[13]*ev[8]; As[14]=A[14]*ev[9]; As[15]=A[15]*ev[10];
  As[16]=A[16]*ev[20];As[17]=A[17]*ev[11];As[18]=A[18]*ev[12];As[19]=A[19]*ev[13];
  As[20]=A[20]*ev[13];As[21]=A[21]*ev[23];As[22]=A[22]*ev[15];As[23]=A[23]*ev[16];
  As[24]=A[24]*ev[4]; As[25]=A[25]*ev[14];As[26]=A[26]*ev[18];As[27]=A[27]*ev[19];
  As[28]=A[28]*ev[7]; As[29]=A[29]*ev[17];As[30]=A[30]*ev[21];As[31]=A[31]*ev[22];
  As[32]=A[32]*ev[10];As[33]=A[33]*ev[20];As[34]=A[34]*ev[23];
}

__device__ __forceinline__ float tree_sum24(const float* a) {
  float s0 = a[0]+a[1],   s1 = a[2]+a[3],   s2 = a[4]+a[5],   s3 = a[6]+a[7];
  float s4 = a[8]+a[9],   s5 = a[10]+a[11], s6 = a[12]+a[13], s7 = a[14]+a[15];
  float s8 = a[16]+a[17], s9 = a[18]+a[19], s10= a[20]+a[21], s11= a[22]+a[23];
  float u0 = s0+s1, u1 = s2+s3, u2 = s4+s5, u3 = s6+s7, u4 = s8+s9, u5 = s10+s11;
  return ((u0+u1) + (u2+u3)) + (u4+u5);
}

// one normalized vector step: f <- normalize((A^T f) * ev)
__device__ __forceinline__ void vec_step(const float* __restrict__ A,
                                         const float* __restrict__ ev,
                                         float* __restrict__ f) {
  float R[NST];
  at_update(A, f, R);
  float al[NST];
  #pragma unroll
  for (int s = 0; s < NST; ++s) al[s] = R[s] * ev[s];
  float z = tree_sum24(al);
  float zr = 1.0f / z;
  #pragma unroll
  for (int s = 0; s < NST; ++s) f[s] = al[s] * zr;
}

__device__ __forceinline__ void load_ev(const float4* __restrict__ etb, int ctx,
                                        float* __restrict__ ev) {
  const float4* ep = etb + ctx * 7;
  #pragma unroll
  for (int j = 0; j < 6; ++j) {
    float4 q = ep[j];
    ev[4*j] = q.x; ev[4*j+1] = q.y; ev[4*j+2] = q.z; ev[4*j+3] = q.w;
  }
}

// ------------------------------------------------------------------
// Prep (merged): block 0 builds A + E tables; other blocks build ctx codes.
// ------------------------------------------------------------------
__global__ __launch_bounds__(256) void k_prep(
    const int* __restrict__ obs,
    const float* __restrict__ wt, const float* __restrict__ we,
    float* __restrict__ etab, float* __restrict__ a35out,
    unsigned char* __restrict__ ctx8)
{
  if (blockIdx.x != 0) {
    int i = ((int)blockIdx.x - 1) * 256 + (int)threadIdx.x;
    int t = i & (TLEN - 1);
    int o0 = obs[i];
    int o1 = (t >= 1) ? obs[i-1] : 4;
    int o2 = (t >= 2) ? obs[i-2] : 4;
    ctx8[i] = (unsigned char)((o2*5 + o1)*4 + o0);
    return;
  }

  __shared__ float lg[NST * 216];
  __shared__ float rmx[NST];
  __shared__ float rrs[NST];
  int tid = threadIdx.x;
  for (int i = tid; i < NST * 216; i += 256) lg[i] = -1e30f;
  __syncthreads();

  for (int e = tid; e < 1073; e += 256) {
    int s, i, j, l, k = -1;
    if (e < 84)        { int ep=e; l=ep&3; int p=ep>>2; if (p<16){i=p>>2;j=p&3;} else {i=4;j=p-16;} s=0; k=ep; }
    else if (e < 104)  { int ep=e-84;  s=1;  i=ep>>2; j=ep&3; l=0; k=84+ep; }
    else if (e < 108)  { int ep=e-104; s=2;  i=ep;    j=0;    l=3; k=104+ep; }
    else if (e < 109)  { s=3; i=0; j=3; l=2; }
    else if (e < 113)  { int ep=e-109; s=4;  i=3; j=2; l=ep;  k=108+ep; }
    else if (e < 129)  { int ep=e-113; s=5;  i=2; j=ep>>2; l=ep&3; k=112+ep; }
    else if (e < 385)  { int ep=e-129; s=6+(ep>>6); int q=ep&63; i=q>>4; j=(q>>2)&3; l=q&3; k=128+ep; }
    else if (e < 401)  { int ep=e-385; s=10; i=ep>>2; j=ep&3; l=3; k=384+ep; }
    else if (e < 405)  { int ep=e-401; s=11; i=ep; j=3; l=0; k=400+ep; }
    else if (e < 409)  { int ep=e-405; s=11; i=ep; j=3; l=2; k=404+ep; }
    else if (e < 412)  { int ep=e-409; s=12; i=3; j=(ep==2)?2:0; l=(ep==1)?2:0; }
    else if (e < 476)  { int ep=e-412; s=13; i=ep>>4; j=(ep>>2)&3; l=ep&3; k=408+ep; }
    else if (e < 1052) { int ep=e-476; s=14+(ep>>6); int q=ep&63; i=q>>4; j=(q>>2)&3; l=q&3; k=472+ep; }
    else if (e < 1068) { int ep=e-1052; s=23; i=ep>>2; j=ep&3; l=5; k=1048+ep; }
    else if (e < 1072) { int ep=e-1068; s=23; i=ep; j=5; l=5; k=1064+ep; }
    else               { s=23; i=5; j=5; l=5; }
    float v = (k < 0) ? 1.0f : we[k];
    lg[s*216 + i*36 + j*6 + l] = v;
  }
  __syncthreads();

  if (tid < NST) {
    float mx = -1e30f;
    for (int x = 0; x < 216; ++x) mx = fmaxf(mx, lg[tid*216 + x]);
    float sum = 0.f;
    for (int x = 0; x < 216; ++x) sum += expf(lg[tid*216 + x] - mx);
    rmx[tid] = mx;
    rrs[tid] = 1.0f / sum;
  }
  __syncthreads();

  if (tid < NCTX) {
    int c2 = tid / 20, c1 = (tid >> 2) % 5, c0 = tid & 3;
    int x = c2*36 + c1*6 + c0;
    float v[NST];
    float m = 1e-30f;
    for (int s = 0; s < NST; ++s) {
      v[s] = expf(lg[s*216 + x] - rmx[s]) * rrs[s];
      m = fmaxf(m, v[s]);
    }
    float im = 1.0f / m;
    for (int s = 0; s < NST; ++s) etab[tid*ESTR + s] = v[s] * im;
    etab[tid*ESTR + 24] = logf(m);
    etab[tid*ESTR + 25] = 0.f; etab[tid*ESTR + 26] = 0.f; etab[tid*ESTR + 27] = 0.f;
  }

  if (tid == 0) {
    float w[10];
    for (int q = 0; q < 10; ++q) w[q] = wt[q];
    float la[35];
    float d2 = 1.f - w[9]*w[9];
    float d3 = 1.f - w[9]*w[9]*w[9];
    la[0]=1.f-w[0]; la[1]=w[0];
    la[2]=1.f; la[3]=1.f;
    la[4]=w[1]; la[5]=w[3]; la[6]=d2; la[7]=d3;
    la[8]=1.f; la[9]=1.f;
    la[10]=w[2]; la[11]=w[4]; la[12]=d2;
    la[13]=1.f; la[14]=1.f;
    la[15]=1.f-w[5]; la[16]=w[5];
    la[17]=1.f; la[18]=1.f; la[19]=1.f;
    la[20]=1.f; la[21]=1.f;
    la[22]=1.f; la[23]=1.f;
    la[24]=w[6]; la[25]=1.f-w[6];
    la[26]=1.f; la[27]=1.f;
    la[28]=w[7]; la[29]=1.f-w[7];
    la[30]=1.f; la[31]=1.f;
    la[32]=w[8]; la[33]=1.f-w[8];
    la[34]=1.f;
    const int rs[25] = {0,2,3,4,8,9,10,13,14,15,17,18,19,20,22,23,24,26,27,28,30,31,32,34,35};
    for (int r = 0; r < 24; ++r) {
      float mx = -1e30f;
      for (int e = rs[r]; e < rs[r+1]; ++e) mx = fmaxf(mx, la[e]);
      float sm = 0.f;
      for (int e = rs[r]; e < rs[r+1]; ++e) sm += expf(la[e] - mx);
      float inv = 1.0f / sm;
      for (int e = rs[r]; e < rs[r+1]; ++e) a35out[e] = expf(la[e] - mx) * inv;
    }
  }
}

// ------------------------------------------------------------------
// Phase A (coarse, CBT chunks of L=TLEN/CBT): thread = (chunk, batch,
// 4 columns). Per step: shared scaled edges As[35] (ev folded once),
// then 35 FMA per column. ctx bytes prefetched one word per 4 steps.
// Columns renormalized every 16 steps and at store (bf16 M).
// ------------------------------------------------------------------
template<int CBT>
__global__ __launch_bounds__(256) void k_phaseA(
    const unsigned char* __restrict__ ctx8,
    const float* __restrict__ etab,
    const float* __restrict__ a35,
    unsigned short* __restrict__ M,
    float* __restrict__ lsbuf,
    float* __restrict__ csb)
{
  constexpr int BPC = (BATCH * 6) / 256;   // 12 blocks per chunk
  constexpr int L = TLEN / CBT;
  __shared__ __align__(16) float et[NCTX * ESTR];
  for (int i = threadIdx.x; i < NCTX * ESTR; i += 256) et[i] = etab[i];
  float A[35];
  #pragma unroll
  for (int e = 0; e < 35; ++e) A[e] = sload(a35 + e);
  __syncthreads();

  int c    = (int)blockIdx.x / BPC;
  int il   = ((int)blockIdx.x % BPC) * 256 + (int)threadIdx.x;  // 0..3071
  int b    = il / 6;
  int q    = il % 6;
  int col0 = q * 4;

  float m[4][NST];
  #pragma unroll
  for (int u = 0; u < 4; ++u)
    #pragma unroll
    for (int s = 0; s < NST; ++s) m[u][s] = (s == col0 + u) ? 1.0f : 0.0f;

  const unsigned char* cb = ctx8 + (size_t)b * TLEN;
  const float4* etb = (const float4*)et;
  float ls = 0.0f;
  float lsc[4] = {0.f, 0.f, 0.f, 0.f};
  const int t0 = c * L;
  if (c == 0) {
    int ctx0 = cb[0];
    ls = logf(et[ctx0*ESTR]) + et[ctx0*ESTR + 24];   // ll0 = log B[0,4,4,obs0]
  }

  for (int kk = 0; kk < L/4; ++kk) {
    unsigned w = *(const unsigned*)(cb + t0 + kk*4);
    #pragma unroll
    for (int j = 0; j < 4; ++j) {
      if (c == 0 && kk == 0 && j == 0) continue;   // t=0 handled via ll0
      int ctx = (int)((w >> (8*j)) & 0xFFu);
      float ev[NST];
      load_ev(etb, ctx, ev);
      ls += et[ctx*ESTR + 24];
      float As[35];
      scale_edges(A, ev, As);
      #pragma unroll
      for (int u = 0; u < 4; ++u) {
        float R[NST];
        at_update(As, m[u], R);
        #pragma unroll
        for (int s = 0; s < NST; ++s) m[u][s] = R[s];
      }
    }
    if ((kk & 3) == 3 && kk + 1 < L/4) {           // after steps 16,32,48
      #pragma unroll
      for (int u = 0; u < 4; ++u) {
        float cmax = 0.f;
        #pragma unroll
        for (int s = 0; s < NST; ++s) cmax = fmaxf(cmax, m[u][s]);
        if (cmax > 1e-35f) {
          float r = 1.0f / cmax;
          lsc[u] += __logf(cmax);
          #pragma unroll
          for (int s = 0; s < NST; ++s) m[u][s] *= r;
        } else {
          lsc[u] = -1e30f;
          #pragma unroll
          for (int s = 0; s < NST; ++s) m[u][s] = 0.f;
        }
      }
    }
  }

  // final renorm (max entry of each stored column = 1 -> best bf16 precision)
  #pragma unroll
  for (int u = 0; u < 4; ++u) {
    float cmax = 0.f;
    #pragma unroll
    for (int s = 0; s < NST; ++s) cmax = fmaxf(cmax, m[u][s]);
    if (cmax > 1e-35f) {
      float r = 1.0f / cmax;
      lsc[u] += __logf(cmax);
      #pragma unroll
      for (int s = 0; s < NST; ++s) m[u][s] *= r;
    } else {
      lsc[u] = -1e30f;
      #pragma unroll
      for (int s = 0; s < NST; ++s) m[u][s] = 0.f;
    }
  }

  size_t base = ((size_t)(c*BATCH + b)) * (NST*NST);
  #pragma unroll
  for (int s = 0; s < NST; ++s) {
    ushort4 wv;
    wv.x = f2bf(m[0][s]); wv.y = f2bf(m[1][s]);
    wv.z = f2bf(m[2][s]); wv.w = f2bf(m[3][s]);
    *(ushort4*)(M + base + s*NST + col0) = wv;
  }
  float4 cw = make_float4(lsc[0], lsc[1], lsc[2], lsc[3]);
  *(float4*)(csb + (size_t)(c*BATCH + b)*NST + col0) = cw;
  if (q == 0) lsbuf[c*BATCH + b] = ls;
}

// ------------------------------------------------------------------
// Phase B: scan over CBT coarse chunks. Block = 1 wave = 2 batches
// (32 lanes each). Every lane holds the FULL v[24] and cs[24] replicated;
// matvec fully in-lane; only z needs a cross-lane reduce; the fn -> v
// transpose goes through one LDS write + float4 reads.
// ------------------------------------------------------------------
template<int CBT>
__global__ __launch_bounds__(64) void k_phaseB(
    const unsigned short* __restrict__ M,
    const float* __restrict__ lsbuf,
    const float* __restrict__ csb,
    float* __restrict__ vbc,
    float* __restrict__ alphas,
    float* __restrict__ llout)
{
  __shared__ __align__(16) float xfer[64];
  int lane = (int)threadIdx.x;
  int sub  = lane >> 5;
  int g    = lane & 31;
  bool act = g < NST;
  int gi   = act ? g : 0;
  int b    = (int)blockIdx.x * 2 + sub;

  float v[NST];
  #pragma unroll
  for (int j = 0; j < NST; ++j) v[j] = (j == 0) ? 1.0f : 0.0f;

  if (act) {
    vbc[((size_t)b*CBT + 0)*NST + g] = (g == 0) ? 1.0f : 0.0f;
    alphas[(size_t)b*TLEN*NST + g]   = (g == 0) ? 1.0f : 0.0f;   // t = 0 row
  }

  uint4  cM0, cM1, cM2;
  float4 cS0, cS1, cS2, cS3, cS4, cS5;
  float  cLS;
  {
    const uint4* p = (const uint4*)(M + (((size_t)b)*NST + gi)*NST);
    cM0 = p[0]; cM1 = p[1]; cM2 = p[2];
    const float4* s = (const float4*)(csb + (size_t)b*NST);
    cS0 = s[0]; cS1 = s[1]; cS2 = s[2]; cS3 = s[3]; cS4 = s[4]; cS5 = s[5];
    cLS = lsbuf[b];
  }

  float ll = 0.0f;
  for (int c = 0; c < CBT; ++c) {
    uint4  nM0, nM1, nM2;
    float4 nS0, nS1, nS2, nS3, nS4, nS5;
    float  nLS = 0.f;
    nM0 = nM1 = nM2 = make_uint4(0,0,0,0);
    nS0 = nS1 = nS2 = nS3 = nS4 = nS5 = make_float4(-1e30f,-1e30f,-1e30f,-1e30f);
    if (c + 1 < CBT) {
      const uint4* p = (const uint4*)(M + (((size_t)((c+1)*BATCH + b))*NST + gi)*NST);
      nM0 = p[0]; nM1 = p[1]; nM2 = p[2];
      const float4* s = (const float4*)(csb + (size_t)((c+1)*BATCH + b)*NST);
      nS0 = s[0]; nS1 = s[1]; nS2 = s[2]; nS3 = s[3]; nS4 = s[4]; nS5 = s[5];
      nLS = lsbuf[(c+1)*BATCH + b];
    }

    float cs[NST];
    cs[0]=cS0.x; cs[1]=cS0.y; cs[2]=cS0.z; cs[3]=cS0.w;
    cs[4]=cS1.x; cs[5]=cS1.y; cs[6]=cS1.z; cs[7]=cS1.w;
    cs[8]=cS2.x; cs[9]=cS2.y; cs[10]=cS2.z; cs[11]=cS2.w;
    cs[12]=cS3.x; cs[13]=cS3.y; cs[14]=cS3.z; cs[15]=cS3.w;
    cs[16]=cS4.x; cs[17]=cS4.y; cs[18]=cS4.z; cs[19]=cS4.w;
    cs[20]=cS5.x; cs[21]=cS5.y; cs[22]=cS5.z; cs[23]=cS5.w;

    float csm = cs[0];
    #pragma unroll
    for (int j = 1; j < NST; ++j) csm = fmaxf(csm, cs[j]);

    float p[NST];
    #pragma unroll
    for (int j = 0; j < NST; ++j) p[j] = v[j] * __expf(cs[j] - csm);

    float mr[NST];
    {
      unsigned uu[12] = {cM0.x,cM0.y,cM0.z,cM0.w, cM1.x,cM1.y,cM1.z,cM1.w,
                         cM2.x,cM2.y,cM2.z,cM2.w};
      #pragma unroll
      for (int j = 0; j < 12; ++j) {
        mr[2*j]   = __uint_as_float(uu[j] << 16);
        mr[2*j+1] = __uint_as_float(uu[j] & 0xFFFF0000u);
      }
    }

    float pr[NST];
    #pragma unroll
    for (int j = 0; j < NST; ++j) pr[j] = mr[j] * p[j];
    float nv = act ? tree_sum24(pr) : 0.f;

    float z = nv;
    #pragma unroll
    for (int o = 1; o < 32; o <<= 1) z += __shfl_xor(z, o, 32);

    float fn = nv / z;
    ll += __logf(z) + csm + cLS;

    if (act && c + 1 < CBT) vbc[((size_t)b*CBT + c + 1)*NST + g] = fn;

    xfer[sub*32 + g] = fn;
    __syncthreads();
    {
      const float4* x4 = (const float4*)(&xfer[sub*32]);
      float4 q0 = x4[0], q1 = x4[1], q2 = x4[2],
             q3 = x4[3], q4 = x4[4], q5 = x4[5];
      v[0]=q0.x; v[1]=q0.y; v[2]=q0.z; v[3]=q0.w;
      v[4]=q1.x; v[5]=q1.y; v[6]=q1.z; v[7]=q1.w;
      v[8]=q2.x; v[9]=q2.y; v[10]=q2.z; v[11]=q2.w;
      v[12]=q3.x; v[13]=q3.y; v[14]=q3.z; v[15]=q3.w;
      v[16]=q4.x; v[17]=q4.y; v[18]=q4.z; v[19]=q4.w;
      v[20]=q5.x; v[21]=q5.y; v[22]=q5.z; v[23]=q5.w;
    }
    __syncthreads();

    cM0 = nM0; cM1 = nM1; cM2 = nM2;
    cS0 = nS0; cS1 = nS1; cS2 = nS2; cS3 = nS3; cS4 = nS4; cS5 = nS5;
    cLS = nLS;
  }
  if (g == 0) llout[b] = ll;
}

// ------------------------------------------------------------------
// Expand: one thread per (b, coarse chunk). Replays vector steps to emit
// the fine boundaries (CF total) from the coarse boundary vbc[g].
// ------------------------------------------------------------------
template<int CBT>
__global__ __launch_bounds__(64) void k_expand(
    const unsigned char* __restrict__ ctx8,
    const float* __restrict__ etab,
    const float* __restrict__ a35,
    const float* __restrict__ vbc,
    float* __restrict__ vbf)
{
  constexpr int FPC = CF / CBT;
  constexpr int SL  = TLEN / CF;     // 8
  __shared__ __align__(16) float et[NCTX * ESTR];
  for (int i = threadIdx.x; i < NCTX * ESTR; i += 64) et[i] = etab[i];
  float A[35];
  #pragma unroll
  for (int e = 0; e < 35; ++e) A[e] = sload(a35 + e);
  __syncthreads();

  int i = (int)blockIdx.x * 64 + (int)threadIdx.x;
  int b = i / CBT;
  int g = i % CBT;

  float f[NST];
  {
    const float4* p = (const float4*)(vbc + ((size_t)b*CBT + g) * NST);
    #pragma unroll
    for (int j = 0; j < 6; ++j) {
      float4 q = p[j];
      f[4*j] = q.x; f[4*j+1] = q.y; f[4*j+2] = q.z; f[4*j+3] = q.w;
    }
  }
  {
    float4* o = (float4*)(vbf + ((size_t)b*CF + g*FPC) * NST);
    o[0] = make_float4(f[0],f[1],f[2],f[3]);
    o[1] = make_float4(f[4],f[5],f[6],f[7]);
    o[2] = make_float4(f[8],f[9],f[10],f[11]);
    o[3] = make_float4(f[12],f[13],f[14],f[15]);
    o[4] = make_float4(f[16],f[17],f[18],f[19]);
    o[5] = make_float4(f[20],f[21],f[22],f[23]);
  }

  const unsigned char* cb = ctx8 + (size_t)b * TLEN;
  const float4* etb = (const float4*)et;
  int t = g * (TLEN / CBT);
  for (int k3 = 1; k3 < FPC; ++k3) {
    for (int k = 0; k < SL; ++k) {
      if (t != 0) {
        int ctx = cb[t];
        float ev[NST];
        load_ev(etb, ctx, ev);
        vec_step(A, ev, f);
      }
      ++t;
    }
    float4* o = (float4*)(vbf + ((size_t)b*CF + g*FPC + k3) * NST);
    o[0] = make_float4(f[0],f[1],f[2],f[3]);
    o[1] = make_float4(f[4],f[5],f[6],f[7]);
    o[2] = make_float4(f[8],f[9],f[10],f[11]);
    o[3] = make_float4(f[12],f[13],f[14],f[15]);
    o[4] = make_float4(f[16],f[17],f[18],f[19]);
    o[5] = make_float4(f[20],f[21],f[22],f[23]);
  }
}

// ------------------------------------------------------------------
// Phase C (fine, CF chunks of 8 steps): replay the recurrence inside each
// fine chunk, stream alphas with float4 stores.
// ------------------------------------------------------------------
__global__ __launch_bounds__(256) void k_phaseC(
    const unsigned char* __restrict__ ctx8,
    const float* __restrict__ etab,
    const float* __restrict__ a35,
    const float* __restrict__ vbf,
    float* __restrict__ alphas)
{
  constexpr int L = TLEN / CF;   // 8
  __shared__ __align__(16) float et[NCTX * ESTR];
  for (int i = threadIdx.x; i < NCTX * ESTR; i += 256) et[i] = etab[i];
  float A[35];
  #pragma unroll
  for (int e = 0; e < 35; ++e) A[e] = sload(a35 + e);
  __syncthreads();

  int i = (int)blockIdx.x * 256 + (int)threadIdx.x;
  int b = i / CF;
  int c = i % CF;

  float f[NST];
  {
    const float4* p = (const float4*)(vbf + ((size_t)b*CF + c) * NST);
    #pragma unroll
    for (int j = 0; j < 6; ++j) {
      float4 q = p[j];
      f[4*j] = q.x; f[4*j+1] = q.y; f[4*j+2] = q.z; f[4*j+3] = q.w;
    }
  }

  const unsigned char* cb = ctx8 + (size_t)b * TLEN;
  const float4* etb = (const float4*)et;
  int t0 = c * L;
  for (int k = 0; k < L; ++k) {
    int t = t0 + k;
    if (t == 0) continue;      // t=0 row written by phase B
    int ctx = cb[t];
    float ev[NST];
    load_ev(etb, ctx, ev);
    vec_step(A, ev, f);

    float4* o4 = (float4*)(alphas + ((size_t)b*TLEN + t) * NST);
    o4[0] = make_float4(f[0],  f[1],  f[2],  f[3]);
    o4[1] = make_float4(f[4],  f[5],  f[6],  f[7]);
    o4[2] = make_float4(f[8],  f[9],  f[10], f[11]);
    o4[3] = make_float4(f[12], f[13], f[14], f[15]);
    o4[4] = make_float4(f[16], f[17], f[18], f[19]);
    o4[5] = make_float4(f[20], f[21], f[22], f[23]);
  }
}

// ------------------------------------------------------------------
template<int CBT>
static void run_pipeline(const unsigned char* ctx8, const float* etab, const float* a35,
                         unsigned short* mbuf, float* lsb, float* csb,
                         float* vbc, float* vbf,
                         float* alphas, float* llout, hipStream_t stream)
{
  k_phaseA<CBT><<<CBT * ((BATCH * 6) / 256), 256, 0, stream>>>(ctx8, etab, a35, mbuf, lsb, csb);
  k_phaseB<CBT><<<BATCH / 2, 64, 0, stream>>>(mbuf, lsb, csb, vbc, alphas, llout);
  k_expand<CBT><<<(BATCH * CBT) / 64, 64, 0, stream>>>(ctx8, etab, a35, vbc, vbf);
  k_phaseC<<<(BATCH * CF) / 256, 256, 0, stream>>>(ctx8, etab, a35, vbf, alphas);
}

extern "C" void kernel_launch(void* const* d_in, const int* in_sizes, int n_in,
                              void* d_out, int out_size, void* d_ws, size_t ws_size,
                              hipStream_t stream)
{
  (void)in_sizes; (void)n_in; (void)out_size;
  const int*   obs = (const int*)d_in[0];
  const float* wt  = (const float*)d_in[1];
  const float* we  = (const float*)d_in[2];
  // d_in[3] (init_kernel) is mathematically unused: softmax of 1 element == 1.

  float* out    = (float*)d_out;
  float* alphas = out;
  float* llout  = out + (size_t)BATCH * TLEN * NST;

  char* ws = (char*)d_ws;
  const size_t ETAB_OFF = 0;                                        // 11200 B
  const size_t A_OFF    = 12 * 1024;
  const size_t CTX_OFF  = 16 * 1024;                                // 1 MiB
  const size_t LS_OFF   = CTX_OFF + (size_t)BATCH * TLEN;           // 64*512*4    = 128 KiB
  const size_t CS_OFF   = LS_OFF + (size_t)64 * BATCH * 4;          // 64*512*24*4 = 3 MiB
  const size_t VBC_OFF  = CS_OFF + (size_t)64 * BATCH * NST * 4;    // 512*64*24*4 = 3 MiB
  const size_t VBF_OFF  = VBC_OFF + (size_t)BATCH * 64 * NST * 4;   // 512*CF*24*4 = 12.6 MiB
  const size_t M_OFF    = VBF_OFF + (size_t)BATCH * CF * NST * 4;

  float* etab = (float*)(ws + ETAB_OFF);
  float* a35  = (float*)(ws + A_OFF);
  unsigned char* ctx8 = (unsigned char*)(ws + CTX_OFF);
  float* lsb  = (float*)(ws + LS_OFF);
  float* csb  = (float*)(ws + CS_OFF);
  float* vbc  = (float*)(ws + VBC_OFF);
  float* vbf  = (float*)(ws + VBF_OFF);
  unsigned short* mbuf = (unsigned short*)(ws + M_OFF);

  k_prep<<<1 + (BATCH * TLEN) / 256, 256, 0, stream>>>(obs, wt, we, etab, a35, ctx8);

  const size_t need64 = M_OFF + (size_t)64 * BATCH * NST * NST * 2;   // ~57.5 MB
  if (ws_size >= need64) {
    run_pipeline<64>(ctx8, etab, a35, mbuf, lsb, csb, vbc, vbf, alphas, llout, stream);
  } else {
    run_pipeline<32>(ctx8, etab, a35, mbuf, lsb, csb, vbc, vbf, alphas, llout, stream);
  }
}